// Round 10
// baseline (325.653 us; speedup 1.0000x reference)
//
#include <hip/hip_runtime.h>

#define SUPPORT 512
#define TARGET  65024
#define NCLS    64
#define NQUAD   (TARGET / 4)                 // 16256
#define NCHUNK  (TARGET * SUPPORT / 4096)    // 8128 chunks of 8 rows
#define G       768
#define DB      (G / 4)                      // 192 direct blocks
#define PB      (G - DB)                     // 576 pos-hist blocks

struct Accum {
    float hist_fr_sp[8][80];    // spread Σfrac per bin (pos elements)
    float hist_cnt_sp[8][80];   // spread counts per bin
    float sum_all[8];
    float nll_sum[8];
    int   tgt_cnt[NCLS];
    int   sup_cnt[NCLS];
    unsigned bar;               // grid barrier counter (memset to 0 each launch)
};

__device__ __forceinline__ void lds_fadd(float* p, float v) {
    __hip_atomic_fetch_add(p, v, __ATOMIC_RELAXED, __HIP_MEMORY_SCOPE_WORKGROUP);
}
__device__ __forceinline__ float agent_loadf(const float* p) {
    return __hip_atomic_load(p, __ATOMIC_RELAXED, __HIP_MEMORY_SCOPE_AGENT);
}
__device__ __forceinline__ int agent_loadi(const int* p) {
    return __hip_atomic_load(p, __ATOMIC_RELAXED, __HIP_MEMORY_SCOPE_AGENT);
}
// Monotonic-counter grid barrier. Safe: all G blocks co-resident by construction.
__device__ __forceinline__ void grid_barrier(unsigned* cnt, unsigned target) {
    __syncthreads();
    if (threadIdx.x == 0) {
        __hip_atomic_fetch_add(cnt, 1u, __ATOMIC_ACQ_REL, __HIP_MEMORY_SCOPE_AGENT);
        while (__hip_atomic_load(cnt, __ATOMIC_ACQUIRE, __HIP_MEMORY_SCOPE_AGENT) < target)
            __builtin_amdgcn_s_sleep(2);
    }
    __syncthreads();
}

__global__ __launch_bounds__(256, 4) void fused_kernel(const float* __restrict__ logits,
                                                       const float* __restrict__ ip,
                                                       const int* __restrict__ labels,
                                                       Accum* __restrict__ ws,
                                                       float* __restrict__ out) {
    __shared__ float SA[76 * 32];     // phase A: pos {hfr|hcnt}; phase B: A-table
    __shared__ float SB[76 * 32];     // phase A: CSR ints / direct ltc; phase B: B-table
    __shared__ float Sfr[80], Cnt[80];
    __shared__ float Atab[80], Btab[80];
    __shared__ float red[8];

    const int tid = threadIdx.x;
    const int bid = blockIdx.x;

    // ================= phase A =================
    if (bid < DB) {
        // ---- direct loss: 4 rows per wave, 16-lane group per row
        int* ltc = (int*)SB;
        if (tid < NCLS) ltc[tid] = 0;
        __syncthreads();
        const int wid  = tid >> 6;
        const int lane = tid & 63;
        const int sub  = lane >> 4;
        const int grpb = lane & ~15;
        float lsum = 0.0f;
        for (int q = bid * 4 + wid; q < NQUAD; q += DB * 4) {
            const float4 x = reinterpret_cast<const float4*>(logits)[q * 64 + lane];
            const int lab  = labels[SUPPORT + q * 4 + sub];
            float m = fmaxf(fmaxf(x.x, x.y), fmaxf(x.z, x.w));
            #pragma unroll
            for (int off = 1; off < 16; off <<= 1) m = fmaxf(m, __shfl_xor(m, off));
            float e = __expf(x.x - m) + __expf(x.y - m) + __expf(x.z - m) + __expf(x.w - m);
            #pragma unroll
            for (int off = 1; off < 16; off <<= 1) e += __shfl_xor(e, off);
            const int l3 = lab & 3;
            const float sel = l3 == 0 ? x.x : l3 == 1 ? x.y : l3 == 2 ? x.z : x.w;
            const float xl = __shfl(sel, grpb + (lab >> 2));
            if ((lane & 15) == 0) { lsum += m + __logf(e) - xl; atomicAdd(&ltc[lab], 1); }
        }
        #pragma unroll
        for (int off = 1; off < 64; off <<= 1) lsum += __shfl_xor(lsum, off);
        if (lane == 0) red[wid] = lsum;
        __syncthreads();
        if (tid == 0) unsafeAtomicAdd(&ws->nll_sum[bid & 7], red[0] + red[1] + red[2] + red[3]);
        if (tid < NCLS) { int v = ltc[tid]; if (v) atomicAdd(&ws->tgt_cnt[tid], v); }
    } else {
        // ---- pos (Sfr,Cnt) histogram with block-local CSR build
        float* hfr  = SA;                    // [76][8]
        float* hcnt = SA + 76 * 8;
        int* colL = (int*)SB;                // [512]
        int* offL = (int*)SB + 512;          // [65]
        int* cntL = (int*)SB + 577;          // [64]
        int* curL = (int*)SB + 641;          // [64]
        for (int i = tid; i < 76 * 16; i += 256) SA[i] = 0.0f;
        if (tid < NCLS) cntL[tid] = 0;
        __syncthreads();
        for (int j = tid; j < SUPPORT; j += 256) atomicAdd(&cntL[labels[j]], 1);
        __syncthreads();
        if (tid == 0) {
            int o = 0;
            for (int i = 0; i < NCLS; ++i) { offL[i] = o; curL[i] = o; o += cntL[i]; }
            offL[NCLS] = o;
        }
        __syncthreads();
        for (int j = tid; j < SUPPORT; j += 256) {
            const int c = labels[j];
            colL[atomicAdd(&curL[c], 1)] = j;
        }
        __syncthreads();
        const int sl = tid & 7;
        for (int r = (bid - DB) * 32 + (tid >> 3); r < TARGET; r += PB * 32) {
            const int c  = labels[SUPPORT + r];
            const int b0 = offL[c], e0 = offL[c + 1];
            const float* rp = ip + (size_t)r * SUPPORT;
            for (int j = b0 + sl; j < e0; j += 8) {
                const float s  = rp[colL[j]];
                const float u  = s * 75.0f;
                const float fl = floorf(u);
                const int idx  = (int)fl;        // 0..74 guaranteed (s in [0,1))
                lds_fadd(&hfr[idx * 8 + sl], u - fl);
                lds_fadd(&hcnt[idx * 8 + sl], 1.0f);
            }
        }
        __syncthreads();
        if (tid < 76) {
            float a = 0.0f, b = 0.0f;
            #pragma unroll
            for (int rr = 0; rr < 8; ++rr) { a += hfr[tid * 8 + rr]; b += hcnt[tid * 8 + rr]; }
            if (a != 0.0f) unsafeAtomicAdd(&ws->hist_fr_sp[bid & 7][tid], a);
            if (b != 0.0f) unsafeAtomicAdd(&ws->hist_cnt_sp[bid & 7][tid], b);
        }
        if (bid == DB && tid < NCLS)
            __hip_atomic_store(&ws->sup_cnt[tid], cntL[tid], __ATOMIC_RELEASE, __HIP_MEMORY_SCOPE_AGENT);
    }

    grid_barrier(&ws->bar, G);

    // ================= phase B: tables + closed-form sum_pos + stream =================
    if (tid < 76) {
        float a = 0.0f, b = 0.0f;
        #pragma unroll
        for (int rr = 0; rr < 8; ++rr) {
            a += agent_loadf(&ws->hist_fr_sp[rr][tid]);
            b += agent_loadf(&ws->hist_cnt_sp[rr][tid]);
        }
        Sfr[tid] = a; Cnt[tid] = b;
    }
    __syncthreads();
    float spos = 0.0f;                 // meaningful in thread 0 (kept in register for phase C)
    if (tid == 0) {
        float prevS = 0.0f, prevN = 0.0f, cacc = 0.0f;
        for (int i = 0; i <= 76; ++i) {
            const float Si = (i < 76) ? Sfr[i] : 0.0f;
            const float Ni = (i < 76) ? Cnt[i] : 0.0f;
            const float Hi = Si + prevN - prevS;     // pos soft-hist H[i]
            cacc += Hi;                              // C[i]
            if (i >= 1) {
                Atab[i - 1] = cacc;                  // A[k]=C[k+1]
                Btab[i - 1] = Hi;                    // B[k]=H[k+1]
                spos += prevN * cacc - prevS * Hi;   // Cnt[k]*C[k+1]-Sfr[k]*H[k+1]
            }
            prevS = Si; prevN = Ni;
        }
        for (int i = 76; i < 80; ++i) { Atab[i] = 0.0f; Btab[i] = 0.0f; }
    }
    __syncthreads();
    for (int i = tid; i < 76 * 32; i += 256) {       // 32-way replicated split tables
        const int idx = i >> 5;
        SA[i] = Atab[idx];
        SB[i] = Btab[idx];
    }
    __syncthreads();

    const int c32 = tid & 31;                        // bank == c32: conflict-free
    float s0 = 0.0f, s1 = 0.0f;
    float4 qa0, qa1, qa2, qa3, qb0, qb1, qb2, qb3;
    const float4* ip4 = reinterpret_cast<const float4*>(ip);

#define LD(Q0,Q1,Q2,Q3,C) { const float4* p = ip4 + (size_t)(C) * 1024 + tid; \
                            Q0 = p[0]; Q1 = p[256]; Q2 = p[512]; Q3 = p[768]; }
#define PE(S, ACC) { const float u = (S) * 75.0f; const float fl = floorf(u);   \
                     const int idx = (int)fl;                                   \
                     const float a = SA[(idx << 5) + c32];                      \
                     const float b = SB[(idx << 5) + c32];                      \
                     ACC += fmaf(fl - u, b, a); }
#define PR(Q0,Q1,Q2,Q3) { PE(Q0.x,s0) PE(Q0.y,s1) PE(Q0.z,s0) PE(Q0.w,s1) \
                          PE(Q1.x,s0) PE(Q1.y,s1) PE(Q1.z,s0) PE(Q1.w,s1) \
                          PE(Q2.x,s0) PE(Q2.y,s1) PE(Q2.z,s0) PE(Q2.w,s1) \
                          PE(Q3.x,s0) PE(Q3.y,s1) PE(Q3.z,s0) PE(Q3.w,s1) }

    int c0 = bid;                                    // bid < G <= NCHUNK always
    LD(qa0,qa1,qa2,qa3, c0);
    while (c0 < NCHUNK) {
        const int c1 = c0 + G;
        if (c1 < NCHUNK) LD(qb0,qb1,qb2,qb3, c1);
        PR(qa0,qa1,qa2,qa3);
        const int c2 = c0 + 2 * G;
        if (c2 < NCHUNK) LD(qa0,qa1,qa2,qa3, c2);
        if (c1 < NCHUNK) PR(qb0,qb1,qb2,qb3);
        c0 = c2;
    }
#undef LD
#undef PE
#undef PR

    float s_all = s0 + s1;
    #pragma unroll
    for (int off = 1; off < 64; off <<= 1) s_all += __shfl_xor(s_all, off);
    if ((tid & 63) == 0) red[tid >> 6] = s_all;
    __syncthreads();
    if (tid == 0) unsafeAtomicAdd(&ws->sum_all[bid & 7], red[0] + red[1] + red[2] + red[3]);

    grid_barrier(&ws->bar, 2u * G);

    // ================= phase C =================
    if (bid == 0 && tid == 0) {
        long long pos = 0;
        for (int c = 0; c < NCLS; ++c)
            pos += (long long)agent_loadi(&ws->sup_cnt[c]) * (long long)agent_loadi(&ws->tgt_cnt[c]);
        const long long tot = (long long)TARGET * SUPPORT;
        double S = 0.0, nll = 0.0;
        for (int i = 0; i < 8; ++i) {
            S   += (double)agent_loadf(&ws->sum_all[i]);
            nll += (double)agent_loadf(&ws->nll_sum[i]);
        }
        out[0] = (float)((S - (double)spos) / ((double)pos * (double)(tot - pos)));
        out[1] = (float)(nll / (double)TARGET);
    }
}

// ---------------------------------------------------------------- launch
extern "C" void kernel_launch(void* const* d_in, const int* in_sizes, int n_in,
                              void* d_out, int out_size, void* d_ws, size_t ws_size,
                              hipStream_t stream) {
    const float* logits = (const float*)d_in[0];   // (65024, 64) f32
    const float* ip     = (const float*)d_in[1];   // (65024, 512) f32
    const int*   labels = (const int*)d_in[2];     // (65536,) int
    float* out = (float*)d_out;
    Accum* ws  = (Accum*)d_ws;

    hipMemsetAsync(ws, 0, sizeof(Accum), stream);
    fused_kernel<<<G, 256, 0, stream>>>(logits, ip, labels, ws, out);
}